// Round 8
// baseline (1149.612 us; speedup 1.0000x reference)
//
#include <hip/hip_runtime.h>
#include <math.h>

#define N_ITEMS 100000
#define N_INT   512
#define H       128
#define IPW     8             // items per wave (tracked via octets)
#define IPB     32            // items per block (4 waves)
#define TILE    512           // edges per aggregation tile
#define MAXTILES 2048

typedef unsigned int u32;

__device__ __forceinline__ float wave_sum(float v) {
#pragma unroll
  for (int d = 1; d < 64; d <<= 1) v += __shfl_xor(v, d, 64);
  return v;
}

// K[j][h] = sum_k intent[j][k] * Wk[h][k]
__global__ void k_projK(const float* __restrict__ intent, const float* __restrict__ Wk,
                        float* __restrict__ K) {
  __shared__ float row[H];
  int j = blockIdx.x, h = threadIdx.x;
  row[h] = intent[j * H + h];
  __syncthreads();
  float acc = 0.f;
#pragma unroll 8
  for (int k = 0; k < H; ++k) acc += row[k] * Wk[h * H + k];
  K[j * H + h] = acc;
}

// M[k][j] = (1/sqrt(H)) * sum_a Wq[a][k] * K[j][a]
__global__ void k_projM(const float* __restrict__ Wq, const float* __restrict__ K,
                        float* __restrict__ M) {
  __shared__ float row[H];
  int j = blockIdx.x, k = threadIdx.x;
  row[k] = K[j * H + k];
  __syncthreads();
  float acc = 0.f;
#pragma unroll 8
  for (int a = 0; a < H; ++a) acc += Wq[a * H + k] * row[a];
  M[k * N_INT + j] = acc * 0.08838834764831845f;  // 1/sqrt(128)
}

// sim = item @ M + per-row top-3 + s1.
// r7 lesson: any structure needing a 64-reg accumulator gets AGPR-shuffled by
// the allocator (VGPR_Count pinned at 48-76 across all launch_bounds hints,
// VALUBusy ~31%, 69% stall). This version needs ~35 VGPRs TOTAL:
//   - j on lanes (64 lanes = one 64-j tile, loop jb=0..7) -> acc[8] only
//   - items via wave-UNIFORM addresses -> scalar loads, SGPR-sourced FMAs
//   - M dword loads are fully coalesced; 32KB jb-tile is L1-resident
//   - per-jb top-3 merge via intra-wave LDS transpose (octet per item),
//     NO barriers anywhere.
__global__ __launch_bounds__(256) void k_simtop(
    const float* __restrict__ item, const float* __restrict__ M,
    const float* __restrict__ intent, const float* __restrict__ wa,
    int* __restrict__ topi, float* __restrict__ s1buf, int* __restrict__ counts) {
  __shared__ float xch[4][IPW * 68];  // per-wave exchange tile (no cross-wave use)
  const int tid = threadIdx.x;
  const int lane = tid & 63;
  const int wv = __builtin_amdgcn_readfirstlane(tid >> 6);
  const int ibase = __builtin_amdgcn_readfirstlane(blockIdx.x * IPB + wv * IPW);
  float* xc = &xch[wv][0];
  const int g = lane >> 3;   // octet id = item slot
  const int o = lane & 7;    // position within octet

  // push (v,j) into a descending top-3 with lower-index tiebreak
  auto push3 = [](float v, int j, float& t0, float& t1, float& t2,
                  int& i0, int& i1, int& i2) {
    bool b2 = (v > t2) || (v == t2 && j < i2);
    if (b2) {
      bool b1 = (v > t1) || (v == t1 && j < i1);
      if (b1) {
        bool b0 = (v > t0) || (v == t0 && j < i0);
        if (b0) { t2 = t1; i2 = i1; t1 = t0; i1 = i0; t0 = v; i0 = j; }
        else    { t2 = t1; i2 = i1; t1 = v; i1 = j; }
      } else    { t2 = v; i2 = j; }
    }
  };

  // running top-3 for item (ibase+g), replicated across the octet's 8 lanes
  float rv0 = -INFINITY, rv1 = -INFINITY, rv2 = -INFINITY;
  int ri0 = 0x7fffffff, ri1 = 0x7fffffff, ri2 = 0x7fffffff;

#pragma unroll 1
  for (int jb = 0; jb < 8; ++jb) {
    float acc[IPW];
#pragma unroll
    for (int i = 0; i < IPW; ++i) acc[i] = 0.f;
    const float* mp = M + jb * 64 + lane;
#pragma unroll 2
    for (int k4 = 0; k4 < H / 4; ++k4) {
      float4 av[IPW];
#pragma unroll
      for (int i = 0; i < IPW; ++i)  // uniform addr -> scalar load (s_load)
        av[i] = *reinterpret_cast<const float4*>(item + (size_t)(ibase + i) * H + k4 * 4);
#pragma unroll
      for (int kk = 0; kk < 4; ++kk) {
        float m = mp[(k4 * 4 + kk) * N_INT];  // coalesced dword, L1-resident tile
#pragma unroll
        for (int i = 0; i < IPW; ++i) {
          float a = (kk == 0) ? av[i].x : (kk == 1) ? av[i].y : (kk == 2) ? av[i].z : av[i].w;
          acc[i] += a * m;
        }
      }
    }
    // ---- merge this jb's 64 sims/item into running top-3 (intra-wave only) ----
#pragma unroll
    for (int i = 0; i < IPW; ++i) xc[i * 68 + lane] = acc[i];
    float4 b0 = *reinterpret_cast<const float4*>(xc + g * 68 + o * 8);
    float4 b1 = *reinterpret_cast<const float4*>(xc + g * 68 + o * 8 + 4);
    float tv0 = -INFINITY, tv1 = -INFINITY, tv2 = -INFINITY;
    int ti0 = 0x7fffffff, ti1 = 0x7fffffff, ti2 = 0x7fffffff;
    float lv[8] = {b0.x, b0.y, b0.z, b0.w, b1.x, b1.y, b1.z, b1.w};
#pragma unroll
    for (int t = 0; t < 8; ++t)
      push3(lv[t], jb * 64 + o * 8 + t, tv0, tv1, tv2, ti0, ti1, ti2);
#pragma unroll
    for (int d = 1; d < 8; d <<= 1) {  // butterfly within octet
      float ov0 = __shfl_xor(tv0, d, 64), ov1 = __shfl_xor(tv1, d, 64), ov2 = __shfl_xor(tv2, d, 64);
      int   oi0 = __shfl_xor(ti0, d, 64), oi1 = __shfl_xor(ti1, d, 64), oi2 = __shfl_xor(ti2, d, 64);
      push3(ov0, oi0, tv0, tv1, tv2, ti0, ti1, ti2);
      push3(ov1, oi1, tv0, tv1, tv2, ti0, ti1, ti2);
      push3(ov2, oi2, tv0, tv1, tv2, ti0, ti1, ti2);
    }
    push3(tv0, ti0, rv0, rv1, rv2, ri0, ri1, ri2);
    push3(tv1, ti1, rv0, rv1, rv2, ri0, ri1, ri2);
    push3(tv2, ti2, rv0, rv1, rv2, ri0, ri1, ri2);
  }

  // ---- s1 = leaky(dot(item*wa, intent[j])) : octet-parallel, 16 h per lane ----
  const int gi = ibase + g;
  float s0 = 0.f, s1 = 0.f, s2 = 0.f;
#pragma unroll
  for (int c = 0; c < 4; ++c) {
    int hoff = o * 16 + c * 4;
    float4 it = *reinterpret_cast<const float4*>(item + (size_t)gi * H + hoff);
    float4 w4 = *reinterpret_cast<const float4*>(wa + hoff);
    float4 p  = make_float4(it.x * w4.x, it.y * w4.y, it.z * w4.z, it.w * w4.w);
    float4 i0 = *reinterpret_cast<const float4*>(intent + (size_t)ri0 * H + hoff);
    float4 i1 = *reinterpret_cast<const float4*>(intent + (size_t)ri1 * H + hoff);
    float4 i2 = *reinterpret_cast<const float4*>(intent + (size_t)ri2 * H + hoff);
    s0 += p.x * i0.x + p.y * i0.y + p.z * i0.z + p.w * i0.w;
    s1 += p.x * i1.x + p.y * i1.y + p.z * i1.z + p.w * i1.w;
    s2 += p.x * i2.x + p.y * i2.y + p.z * i2.z + p.w * i2.w;
  }
#pragma unroll
  for (int d = 1; d < 8; d <<= 1) {
    s0 += __shfl_xor(s0, d, 64);
    s1 += __shfl_xor(s1, d, 64);
    s2 += __shfl_xor(s2, d, 64);
  }
  s0 = (s0 > 0.f) ? s0 : 0.2f * s0;
  s1 = (s1 > 0.f) ? s1 : 0.2f * s1;
  s2 = (s2 > 0.f) ? s2 : 0.2f * s2;
  if (o == 0) {
    topi[gi * 3 + 0] = ri0; s1buf[gi * 3 + 0] = s0; atomicAdd(&counts[ri0], 1);
    topi[gi * 3 + 1] = ri1; s1buf[gi * 3 + 1] = s1; atomicAdd(&counts[ri1], 1);
    topi[gi * 3 + 2] = ri2; s1buf[gi * 3 + 2] = s2; atomicAdd(&counts[ri2], 1);
  }
}

// Prefix scan over 512 intent counts + load-balanced tile list (merged).
__global__ void k_scan(const int* __restrict__ counts, int* __restrict__ offs,
                       int* __restrict__ cursor, int* __restrict__ descs,
                       int* __restrict__ ntl) {
  __shared__ int s[N_INT];
  __shared__ int base;
  int t = threadIdx.x;
  if (t == 0) base = 0;
  int c = counts[t];
  s[t] = c;
  __syncthreads();
  for (int off = 1; off < N_INT; off <<= 1) {
    int v = (t >= off) ? s[t - off] : 0;
    __syncthreads();
    s[t] += v;
    __syncthreads();
  }
  int excl = s[t] - c;
  offs[t] = excl;
  cursor[t] = excl;
  if (t == N_INT - 1) offs[N_INT] = s[t];
  int nt = (c + TILE - 1) / TILE;
  int my = atomicAdd(&base, nt);
  for (int k = 0; k < nt; ++k) {
    descs[2 * (my + k)] = t;
    descs[2 * (my + k) + 1] = excl + k * TILE;
  }
  __syncthreads();
  if (t == 0) ntl[0] = base;
}

__global__ void k_scatter(const int* __restrict__ topi, const float* __restrict__ s1buf,
                          int* __restrict__ cursor, int* __restrict__ eitem,
                          float* __restrict__ es1) {
  int gi = blockIdx.x * 256 + threadIdx.x;
  if (gi >= N_ITEMS) return;
#pragma unroll
  for (int e = 0; e < 3; ++e) {
    int j = topi[gi * 3 + e];
    int pos = atomicAdd(&cursor[j], 1);
    eitem[pos] = gi;
    es1[pos] = s1buf[gi * 3 + e];
  }
}

// Per-tile partial aggregation. No segment-max: s1 ~ N(0,1) so exp() is
// overflow-safe and the softmax ratio is mathematically identical.
__global__ __launch_bounds__(256) void k_agg(
    const float* __restrict__ item, const int* __restrict__ offs,
    const int* __restrict__ descs, const int* __restrict__ ntl,
    const int* __restrict__ eitem, const float* __restrict__ es1,
    float* __restrict__ num, float* __restrict__ denom) {
  int bt = blockIdx.x;
  if (bt >= ntl[0]) return;
  int j = descs[2 * bt];
  int beg = descs[2 * bt + 1];
  int end = min(offs[j + 1], beg + TILE);
  __shared__ float red[256];
  __shared__ float rd[2];
  int t = threadIdx.x;
  int h = t & 127, sub = t >> 7;
  float acc = 0.f, dp = 0.f;
  const float* ip = item + h;
#pragma unroll 4
  for (int e = beg + sub; e < end; e += 2) {
    float e1 = expf(es1[e]);
    acc += e1 * ip[(size_t)eitem[e] * H];
    dp += e1;
  }
  red[t] = acc;
  if (h == 0) rd[sub] = dp;
  __syncthreads();
  if (t < 128) atomicAdd(&num[j * H + t], red[t] + red[t + 128]);
  if (t == 0) atomicAdd(&denom[j], rd[0] + rd[1]);
}

// att2 + residual output (normalization of num/denom fused in).
__global__ __launch_bounds__(256) void k_final(
    const float* __restrict__ item, const int* __restrict__ topi,
    const float* __restrict__ num, const float* __restrict__ denom,
    const float* __restrict__ wb, float* __restrict__ out) {
  int tid = threadIdx.x;
  int lane = tid & 63;
  int wv = __builtin_amdgcn_readfirstlane(tid >> 6);
  int gi = blockIdx.x * 4 + wv;
  const float il = item[(size_t)gi * H + lane], ih = item[(size_t)gi * H + 64 + lane];
  const float wbl = wb[lane], wbh = wb[64 + lane];
  int j0 = topi[gi * 3 + 0], j1 = topi[gi * 3 + 1], j2 = topi[gi * 3 + 2];
  float d0 = denom[j0], d1 = denom[j1], d2 = denom[j2];
  float r0 = d0 > 0.f ? 1.f / d0 : 0.f;
  float r1 = d1 > 0.f ? 1.f / d1 : 0.f;
  float r2 = d2 > 0.f ? 1.f / d2 : 0.f;
  float n0l = num[j0 * H + lane] * r0, n0h = num[j0 * H + 64 + lane] * r0;
  float n1l = num[j1 * H + lane] * r1, n1h = num[j1 * H + 64 + lane] * r1;
  float n2l = num[j2 * H + lane] * r2, n2h = num[j2 * H + 64 + lane] * r2;
  float s0 = wave_sum(il * n0l * wbl + ih * n0h * wbh);
  float s1 = wave_sum(il * n1l * wbl + ih * n1h * wbh);
  float s2 = wave_sum(il * n2l * wbl + ih * n2h * wbh);
  s0 = s0 > 0.f ? s0 : 0.2f * s0;
  s1 = s1 > 0.f ? s1 : 0.2f * s1;
  s2 = s2 > 0.f ? s2 : 0.2f * s2;
  float mx = fmaxf(s0, fmaxf(s1, s2));
  float e0 = expf(s0 - mx), e1 = expf(s1 - mx), e2 = expf(s2 - mx);
  float inv = 1.f / (e0 + e1 + e2);
  float w0 = e0 * inv, w1 = e1 * inv, w2 = e2 * inv;
  out[(size_t)gi * H + lane]      = 0.5f * il + 0.5f * (w0 * n0l + w1 * n1l + w2 * n2l);
  out[(size_t)gi * H + 64 + lane] = 0.5f * ih + 0.5f * (w0 * n0h + w1 * n1h + w2 * n2h);
}

extern "C" void kernel_launch(void* const* d_in, const int* in_sizes, int n_in,
                              void* d_out, int out_size, void* d_ws, size_t ws_size,
                              hipStream_t stream) {
  (void)in_sizes; (void)n_in; (void)out_size; (void)ws_size;
  const float* item   = (const float*)d_in[0];
  const float* intent = (const float*)d_in[1];
  const float* Wq     = (const float*)d_in[2];
  const float* Wk     = (const float*)d_in[3];
  const float* wa     = (const float*)d_in[4];
  const float* wb     = (const float*)d_in[5];
  float* out = (float*)d_out;

  char* w = (char*)d_ws;
  auto alloc = [&](size_t bytes) {
    char* p = w;
    w += (bytes + 255) & ~(size_t)255;
    return p;
  };
  float* K      = (float*)alloc(N_INT * H * 4);
  float* M      = (float*)alloc((size_t)H * N_INT * 4);
  int*   topi   = (int*)alloc((size_t)N_ITEMS * 3 * 4);
  float* s1b    = (float*)alloc((size_t)N_ITEMS * 3 * 4);
  int*   offs   = (int*)alloc((N_INT + 1) * 4);
  int*   cursor = (int*)alloc(N_INT * 4);
  int*   eitem  = (int*)alloc((size_t)N_ITEMS * 3 * 4);
  float* es1    = (float*)alloc((size_t)N_ITEMS * 3 * 4);
  int*   descs  = (int*)alloc(MAXTILES * 2 * 4);
  // zero-init group (single contiguous memset): counts, ntl, denom, num
  char*  zbase  = w;
  int*   counts = (int*)alloc(N_INT * 4);
  int*   ntl    = (int*)alloc(4);
  float* denom  = (float*)alloc(N_INT * 4);
  float* num    = (float*)alloc(N_INT * H * 4);
  size_t zlen   = (size_t)(w - zbase);

  hipMemsetAsync(zbase, 0, zlen, stream);
  k_projK<<<N_INT, H, 0, stream>>>(intent, Wk, K);
  k_projM<<<N_INT, H, 0, stream>>>(Wq, K, M);
  k_simtop<<<N_ITEMS / IPB, 256, 0, stream>>>(item, M, intent, wa, topi, s1b, counts);
  k_scan<<<1, N_INT, 0, stream>>>(counts, offs, cursor, descs, ntl);
  k_scatter<<<(N_ITEMS + 255) / 256, 256, 0, stream>>>(topi, s1b, cursor, eitem, es1);
  k_agg<<<MAXTILES, 256, 0, stream>>>(item, offs, descs, ntl, eitem, es1, num, denom);
  k_final<<<N_ITEMS / 4, 256, 0, stream>>>(item, topi, num, denom, wb, out);
}